// Round 14
// baseline (988.439 us; speedup 1.0000x reference)
//
#include <hip/hip_runtime.h>
#include <hip/hip_bf16.h>

#define TT 12
#define HDIM 128
#define ODIM 12
#define TPAD 36        // fp32 GCN gemm LDS pad

typedef short bf16x8 __attribute__((ext_vector_type(8)));
typedef float f32x4  __attribute__((ext_vector_type(4)));

__device__ __forceinline__ float fastrcp(float x) { return __builtin_amdgcn_rcpf(x); }
__device__ __forceinline__ float sigf(float x) { return fastrcp(1.f + __expf(-x)); }
__device__ __forceinline__ float tanh_fast(float x) { return 1.f - 2.f * fastrcp(1.f + __expf(2.f * x)); }
__device__ __forceinline__ unsigned short f2bf(float f) {
    union { float f; unsigned int u; } v; v.f = f;
    unsigned int r = v.u + 0x7FFFu + ((v.u >> 16) & 1u);
    return (unsigned short)(r >> 16);
}

// ---------------- weight pre-pack: ALL mats in 16x16-frag layout ----------------
// slot = mat*128 + ct*4 + ks; element Wpk[(slot*64+lane)*8+j]
// col = ct*16 + (lane&15), k = ks*32 + (lane>>4)*8 + j
// mat0 = Whh0 (offset 0), mat1 = Wih1 (+65536), mat2 = Whh1 (+131072)
__global__ void pack_kernel(const float* __restrict__ Whh0, const float* __restrict__ Wih1,
                            const float* __restrict__ Whh1, unsigned short* __restrict__ Wpk)
{
    int idx = blockIdx.x * 256 + threadIdx.x;
    if (idx >= 384 * 64) return;
    int lane = idx & 63;
    int slot = idx >> 6;
    int mat = slot >> 7;
    int rem = slot & 127;
    const float* src = (mat == 0) ? Whh0 : (mat == 1) ? Wih1 : Whh1;
    int ct = rem >> 2, ks = rem & 3;
    int col = ct * 16 + (lane & 15);
#pragma unroll
    for (int j = 0; j < 8; ++j) {
        int k = ks * 32 + ((lane >> 4) << 3) + j;
        Wpk[((size_t)(slot * 64 + lane) << 3) + j] = f2bf(src[col * 128 + k]);
    }
}

// ---------------- L0: 16x16x32, Whh0 in REGISTERS, dbuf frag hA0, 1 barrier/t ----------------
// One tile (64 nodes) per block; 4 blocks/CU (38 KB LDS).
__global__ __launch_bounds__(512, 2) void lstm_l0_kernel(
    const float* __restrict__ x,              // [N][12][2]
    const unsigned short* __restrict__ Wpk,   // mat0 = Whh0 (16x16 frag)
    const float* __restrict__ Wih0,           // [512][2]
    const float* __restrict__ bih0, const float* __restrict__ bhh0,
    unsigned short* __restrict__ h0f,         // [ntiles][12][8192] bf16 (frag order)
    int N)
{
    __shared__ unsigned short hA0[2][8192];   // 2 x 16 KB
    __shared__ float xls[64 * 24];            // 6 KB

    const int tid  = threadIdx.x;
    const int w    = tid >> 6;
    const int ln   = tid & 63;
    const int l15  = ln & 15;
    const int quad = ln >> 4;
    const int ch   = w * 16 + l15;
    const int chk  = ch >> 5, chq = (ch >> 3) & 3, chj = ch & 7;
    const int tile = blockIdx.x;
    const int nbase = tile * 64;

    // Whh0 fragments -> registers (16 slots = 64 VGPR)
    bf16x8 whr[4][4];
#pragma unroll
    for (int g = 0; g < 4; ++g)
#pragma unroll
        for (int ks = 0; ks < 4; ++ks) {
            int slot = (g * 8 + w) * 4 + ks;
            whr[g][ks] = *(const bf16x8*)(Wpk + ((size_t)(slot * 64 + ln) << 3));
        }

    float wx0[4], wx1[4], br0[4];
#pragma unroll
    for (int g = 0; g < 4; ++g) {
        int row = (g << 7) + ch;
        wx0[g] = Wih0[row * 2 + 0];
        wx1[g] = Wih0[row * 2 + 1];
        br0[g] = bih0[row] + bhh0[row];
    }

    const bf16x8 zv = {0, 0, 0, 0, 0, 0, 0, 0};
    for (int i = tid; i < 64 * 24; i += 512) {
        int n = nbase + i / 24;
        xls[i] = (n < N) ? x[nbase * 24 + i] : 0.f;
    }
    for (int i = tid; i < 1024; i += 512)
        *(bf16x8*)(hA0[0] + i * 8) = zv;
    float c0[16];
#pragma unroll
    for (int r = 0; r < 16; ++r) c0[r] = 0.f;
    __syncthreads();

    for (int t = 0; t < TT; ++t) {
        const unsigned short* usp = hA0[t & 1];
        unsigned short* dst = hA0[(t & 1) ^ 1];

        f32x4 acc[4][4];
#pragma unroll
        for (int rt = 0; rt < 4; ++rt)
#pragma unroll
            for (int g = 0; g < 4; ++g)
#pragma unroll
                for (int e = 0; e < 4; ++e) acc[rt][g][e] = 0.f;

#pragma unroll
        for (int ks = 0; ks < 4; ++ks) {
            bf16x8 a[4];
#pragma unroll
            for (int rt = 0; rt < 4; ++rt)
                a[rt] = *(const bf16x8*)(usp + (((rt * 4 + ks) * 64 + ln) << 3));
#pragma unroll
            for (int g = 0; g < 4; ++g)
#pragma unroll
                for (int rt = 0; rt < 4; ++rt)
                    acc[rt][g] = __builtin_amdgcn_mfma_f32_16x16x32_bf16(a[rt], whr[g][ks], acc[rt][g], 0, 0, 0);
        }

        // overlapped coalesced copy of the STABLE previous h0 (t-1) to global
        if (t > 0) {
            unsigned short* dt = h0f + (((size_t)(tile * TT + (t - 1))) << 13);
#pragma unroll
            for (int it = 0; it < 2; ++it) {
                int i = tid + it * 512;
                *(bf16x8*)(dt + ((size_t)i << 3)) = *(const bf16x8*)(usp + ((size_t)i << 3));
            }
        }

        // epilogue -> dst
#pragma unroll
        for (int rt = 0; rt < 4; ++rt) {
#pragma unroll
            for (int rg = 0; rg < 4; ++rg) {
                int ci = rt * 4 + rg;
                int nd = rt * 16 + quad * 4 + rg;
                float xa = xls[nd * 24 + t * 2 + 0];
                float xb = xls[nd * 24 + t * 2 + 1];
                float zi = acc[rt][0][rg] + br0[0] + wx0[0] * xa + wx1[0] * xb;
                float zf = acc[rt][1][rg] + br0[1] + wx0[1] * xa + wx1[1] * xb;
                float zg = acc[rt][2][rg] + br0[2] + wx0[2] * xa + wx1[2] * xb;
                float zo = acc[rt][3][rg] + br0[3] + wx0[3] * xa + wx1[3] * xb;
                float cn = sigf(zf) * c0[ci] + sigf(zi) * tanh_fast(zg);
                c0[ci] = cn;
                float h = sigf(zo) * tanh_fast(cn);
                dst[(((rt * 4 + chk) * 64 + chq * 16 + quad * 4 + rg) << 3) + chj] = f2bf(h);
            }
        }
        __syncthreads();                       // single barrier per t
    }
    // final copy: h0[TT-1] lives in hA0[TT & 1]
    {
        const unsigned short* usp = hA0[TT & 1];
        unsigned short* dt = h0f + (((size_t)(tile * TT + (TT - 1))) << 13);
#pragma unroll
        for (int it = 0; it < 2; ++it) {
            int i = tid + it * 512;
            *(bf16x8*)(dt + ((size_t)i << 3)) = *(const bf16x8*)(usp + ((size_t)i << 3));
        }
    }
}

// ---------------- L1: 16x16x32, BOTH weight mats in registers, dbuf hA1, 1 barrier/t ----------------
__global__ __launch_bounds__(512, 2) void lstm_l1f_kernel(
    const unsigned short* __restrict__ h0f,   // frag-order h0 tiles
    const unsigned short* __restrict__ Wpk,   // +65536 = Wih1, +131072 = Whh1
    const float* __restrict__ bih1, const float* __restrict__ bhh1,
    float* __restrict__ hbuf,                 // [N][128] fp32 out
    int N)
{
    __shared__ unsigned short hA1[2][8192];   // 2 x 16 KB

    const int tid  = threadIdx.x;
    const int w    = tid >> 6;
    const int ln   = tid & 63;
    const int l15  = ln & 15;
    const int quad = ln >> 4;
    const int ch   = w * 16 + l15;
    const int chk  = ch >> 5, chq = (ch >> 3) & 3, chj = ch & 7;
    const int tile = blockIdx.x;

    bf16x8 wfr[4][4], whr[4][4];
#pragma unroll
    for (int g = 0; g < 4; ++g)
#pragma unroll
        for (int ks = 0; ks < 4; ++ks) {
            int slot = (g * 8 + w) * 4 + ks;
            wfr[g][ks] = *(const bf16x8*)(Wpk + 65536  + ((size_t)(slot * 64 + ln) << 3));
            whr[g][ks] = *(const bf16x8*)(Wpk + 131072 + ((size_t)(slot * 64 + ln) << 3));
        }

    float br1[4];
#pragma unroll
    for (int g = 0; g < 4; ++g) {
        int row = (g << 7) + ch;
        br1[g] = bih1[row] + bhh1[row];
    }

    const bf16x8 zv = {0, 0, 0, 0, 0, 0, 0, 0};
    for (int i = tid; i < 1024; i += 512)
        *(bf16x8*)(hA1[0] + i * 8) = zv;
    float c1[16];
#pragma unroll
    for (int r = 0; r < 16; ++r) c1[r] = 0.f;
    __syncthreads();

    for (int t = 0; t < TT; ++t) {
        const unsigned short* usp = hA1[t & 1];
        unsigned short* dst = hA1[(t & 1) ^ 1];
        const unsigned short* h0t = h0f + (((size_t)(tile * TT + t)) << 13);

        f32x4 acc[4][4];
#pragma unroll
        for (int rt = 0; rt < 4; ++rt)
#pragma unroll
            for (int g = 0; g < 4; ++g)
#pragma unroll
                for (int e = 0; e < 4; ++e) acc[rt][g][e] = 0.f;

#pragma unroll
        for (int ks = 0; ks < 4; ++ks) {
            bf16x8 a0[4];
#pragma unroll
            for (int rt = 0; rt < 4; ++rt)
                a0[rt] = *(const bf16x8*)(h0t + (((rt * 4 + ks) * 64 + ln) << 3));  // 1KB/wave contiguous
            bf16x8 a1[4];
#pragma unroll
            for (int rt = 0; rt < 4; ++rt)
                a1[rt] = *(const bf16x8*)(usp + (((rt * 4 + ks) * 64 + ln) << 3));
#pragma unroll
            for (int g = 0; g < 4; ++g)
#pragma unroll
                for (int rt = 0; rt < 4; ++rt)
                    acc[rt][g] = __builtin_amdgcn_mfma_f32_16x16x32_bf16(a1[rt], whr[g][ks], acc[rt][g], 0, 0, 0);
#pragma unroll
            for (int g = 0; g < 4; ++g)
#pragma unroll
                for (int rt = 0; rt < 4; ++rt)
                    acc[rt][g] = __builtin_amdgcn_mfma_f32_16x16x32_bf16(a0[rt], wfr[g][ks], acc[rt][g], 0, 0, 0);
        }

#pragma unroll
        for (int rt = 0; rt < 4; ++rt) {
#pragma unroll
            for (int rg = 0; rg < 4; ++rg) {
                int ci = rt * 4 + rg;
                float zi = acc[rt][0][rg] + br1[0];
                float zf = acc[rt][1][rg] + br1[1];
                float zg = acc[rt][2][rg] + br1[2];
                float zo = acc[rt][3][rg] + br1[3];
                float cn = sigf(zf) * c1[ci] + sigf(zi) * tanh_fast(zg);
                c1[ci] = cn;
                float h = sigf(zo) * tanh_fast(cn);
                if (t + 1 < TT) {
                    dst[(((rt * 4 + chk) * 64 + chq * 16 + quad * 4 + rg) << 3) + chj] = f2bf(h);
                } else {
                    int n = tile * 64 + rt * 16 + quad * 4 + rg;
                    if (n < N) hbuf[n * HDIM + ch] = h;
                }
            }
        }
        __syncthreads();
    }
}

// ---------------- GCN: CSR build (unchanged) ----------------
__global__ void deg_count_kernel(const int* __restrict__ ei, int* __restrict__ degi, int E)
{
    int e = blockIdx.x * 256 + threadIdx.x;
    if (e < E) atomicAdd(&degi[ei[E + e]], 1);
}

__global__ void row_alloc_kernel(const int* __restrict__ degi, int* __restrict__ row_ptr,
                                 float* __restrict__ dinv, int* __restrict__ counter, int N)
{
    int n = blockIdx.x * 256 + threadIdx.x;
    int lane = threadIdx.x & 63;
    int v = (n < N) ? degi[n] : 0;
    int incl = v;
    for (int off = 1; off < 64; off <<= 1) {
        int u = __shfl_up(incl, off);
        if (lane >= off) incl += u;
    }
    int base = 0;
    if (lane == 63) base = atomicAdd(counter, incl);
    base = __shfl(base, 63);
    if (n < N) {
        row_ptr[n] = base + (incl - v);
        dinv[n] = rsqrtf((float)(v + 1));
    }
}

__global__ void csr_fill_kernel(const int* __restrict__ ei, const int* __restrict__ row_ptr,
                                int* __restrict__ fill, int* __restrict__ csr_src, int E)
{
    int e = blockIdx.x * 256 + threadIdx.x;
    if (e < E) {
        int d = ei[E + e];
        int p = atomicAdd(&fill[d], 1);
        csr_src[row_ptr[d] + p] = ei[e];
    }
}

// ---------------- GCN: transform (fp16 messages; unchanged) ----------------
__global__ __launch_bounds__(256) void gemm128_kernel(const float* __restrict__ X,
                                                      const float* __restrict__ W,
                                                      _Float16* __restrict__ Y, int N)
{
    __shared__ float XT[128 * TPAD];
    const int tid = threadIdx.x;
    const int nbase = blockIdx.x * 32;
    for (int idx = tid; idx < 32 * 128; idx += 256) {
        int m = idx >> 7, k = idx & 127;
        int n = nbase + m;
        XT[k * TPAD + m] = (n < N) ? X[n * HDIM + k] : 0.f;
    }
    __syncthreads();
    const int c  = tid & 63;
    const int mb = (tid >> 6) << 3;
    float acc[8][2];
#pragma unroll
    for (int i = 0; i < 8; ++i) { acc[i][0] = 0.f; acc[i][1] = 0.f; }
    for (int k = 0; k < 128; ++k) {
        const float* xr = &XT[k * TPAD + mb];
        float4 a0 = *(const float4*)(xr);
        float4 a1 = *(const float4*)(xr + 4);
        float a[8] = {a0.x, a0.y, a0.z, a0.w, a1.x, a1.y, a1.z, a1.w};
        float b0 = W[k * HDIM + c];
        float b1 = W[k * HDIM + c + 64];
#pragma unroll
        for (int i = 0; i < 8; ++i) {
            acc[i][0] = fmaf(a[i], b0, acc[i][0]);
            acc[i][1] = fmaf(a[i], b1, acc[i][1]);
        }
    }
#pragma unroll
    for (int i = 0; i < 8; ++i) {
        int n = nbase + mb + i;
        if (n < N) {
            Y[n * HDIM + c]      = (_Float16)acc[i][0];
            Y[n * HDIM + c + 64] = (_Float16)acc[i][1];
        }
    }
}

__global__ void gemm12_kernel(const float* __restrict__ X, const float* __restrict__ W2,
                              _Float16* __restrict__ Y, int N)
{
    int idx = blockIdx.x * 256 + threadIdx.x;
    int n = idx / ODIM, c = idx - n * ODIM;
    if (n >= N) return;
    float acc = 0.f;
    for (int k = 0; k < 128; ++k) acc = fmaf(X[n * HDIM + k], W2[k * ODIM + c], acc);
    Y[n * ODIM + c] = (_Float16)acc;
}

// ---------------- GCN: aggregate with 4-way pipelined gathers ----------------
__global__ __launch_bounds__(256) void agg128_kernel(const _Float16* __restrict__ hW,
        const int* __restrict__ row_ptr, const int* __restrict__ degi,
        const int* __restrict__ csr_src, const float* __restrict__ dinv,
        const float* __restrict__ bias, float* __restrict__ out, int N, int do_relu)
{
    int n = blockIdx.x * 2 + (threadIdx.x >> 7);
    int c = threadIdx.x & 127;
    if (n >= N) return;
    float dn = dinv[n];
    float a0 = (float)hW[n * HDIM + c] * dn * dn;
    float a1 = 0.f, a2 = 0.f, a3 = 0.f;
    int start = row_ptr[n], cnt = degi[n];
    int i = 0;
    for (; i + 4 <= cnt; i += 4) {
        int s0 = csr_src[start + i];
        int s1 = csr_src[start + i + 1];
        int s2 = csr_src[start + i + 2];
        int s3 = csr_src[start + i + 3];
        float w0 = dinv[s0] * dn, w1 = dinv[s1] * dn;
        float w2 = dinv[s2] * dn, w3 = dinv[s3] * dn;
        float v0 = (float)hW[s0 * HDIM + c];
        float v1 = (float)hW[s1 * HDIM + c];
        float v2 = (float)hW[s2 * HDIM + c];
        float v3 = (float)hW[s3 * HDIM + c];
        a0 = fmaf(v0, w0, a0);
        a1 = fmaf(v1, w1, a1);
        a2 = fmaf(v2, w2, a2);
        a3 = fmaf(v3, w3, a3);
    }
    for (; i < cnt; ++i) {
        int s = csr_src[start + i];
        a0 = fmaf((float)hW[s * HDIM + c], dinv[s] * dn, a0);
    }
    float v = (a0 + a1) + (a2 + a3) + bias[c];
    if (do_relu) v = fmaxf(v, 0.f);
    out[n * HDIM + c] = v;
}

__global__ void agg12_kernel(const _Float16* __restrict__ hW, const int* __restrict__ row_ptr,
        const int* __restrict__ degi, const int* __restrict__ csr_src,
        const float* __restrict__ dinv, const float* __restrict__ b2,
        float* __restrict__ out, int N)
{
    int idx = blockIdx.x * 256 + threadIdx.x;
    int n = idx / ODIM, c = idx - n * ODIM;
    if (n >= N) return;
    float dn = dinv[n];
    float a0 = (float)hW[n * ODIM + c] * dn * dn;
    float a1 = 0.f, a2 = 0.f, a3 = 0.f;
    int start = row_ptr[n], cnt = degi[n];
    int i = 0;
    for (; i + 4 <= cnt; i += 4) {
        int s0 = csr_src[start + i];
        int s1 = csr_src[start + i + 1];
        int s2 = csr_src[start + i + 2];
        int s3 = csr_src[start + i + 3];
        a0 = fmaf((float)hW[s0 * ODIM + c], dinv[s0] * dn, a0);
        a1 = fmaf((float)hW[s1 * ODIM + c], dinv[s1] * dn, a1);
        a2 = fmaf((float)hW[s2 * ODIM + c], dinv[s2] * dn, a2);
        a3 = fmaf((float)hW[s3 * ODIM + c], dinv[s3] * dn, a3);
    }
    for (; i < cnt; ++i) {
        int s = csr_src[start + i];
        a0 = fmaf((float)hW[s * ODIM + c], dinv[s] * dn, a0);
    }
    out[n * ODIM + c] = (a0 + a1) + (a2 + a3) + b2[c];
}

extern "C" void kernel_launch(void* const* d_in, const int* in_sizes, int n_in,
                              void* d_out, int out_size, void* d_ws, size_t ws_size,
                              hipStream_t stream)
{
    const float* x     = (const float*)d_in[0];
    const int*   ei    = (const int*)d_in[1];
    const float* Wih0  = (const float*)d_in[2];
    const float* Whh0  = (const float*)d_in[3];
    const float* bih0  = (const float*)d_in[4];
    const float* bhh0  = (const float*)d_in[5];
    const float* Wih1  = (const float*)d_in[6];
    const float* Whh1  = (const float*)d_in[7];
    const float* bih1  = (const float*)d_in[8];
    const float* bhh1  = (const float*)d_in[9];
    const float* W0    = (const float*)d_in[10];
    const float* b0    = (const float*)d_in[11];
    const float* W1    = (const float*)d_in[12];
    const float* b1    = (const float*)d_in[13];
    const float* W2    = (const float*)d_in[14];
    const float* b2    = (const float*)d_in[15];
    float* out = (float*)d_out;

    const int N = in_sizes[0] / (TT * 2);
    const int E = in_sizes[1] / 2;
    const int ntiles = (N + 63) / 64;

    // ---- workspace layout ----
    unsigned short* Wpk = (unsigned short*)d_ws;          // 384 KB
    float* fbase = (float*)((char*)d_ws + 393216);
    float* hbuf = fbase;                                  // N*128 fp32
    float* buf1 = hbuf + (size_t)N * HDIM;                // N*128 (fp16 messages)
    float* buf2 = buf1 + (size_t)N * HDIM;                // N*128 fp32
    float* dinv = buf2 + (size_t)N * HDIM;                // N
    int* degi    = (int*)(dinv + N);                      // N
    int* fill    = degi + N;                              // N
    int* counter = fill + N;                              // 1
    int* row_ptr = counter + 1;                           // N
    int* csr_src = row_ptr + N;                           // E
    size_t h0_off = (((size_t)((char*)(csr_src + E) - (char*)d_ws)) + 255) & ~(size_t)255;
    unsigned short* h0f = (unsigned short*)((char*)d_ws + h0_off);   // ntiles*12*8192 bf16
    _Float16* buf1h = (_Float16*)buf1;

    hipMemsetAsync(degi, 0, (size_t)(2 * N + 1) * sizeof(int), stream);

    pack_kernel<<<(384 * 64 + 255) / 256, 256, 0, stream>>>(Whh0, Wih1, Whh1, Wpk);

    lstm_l0_kernel<<<ntiles, 512, 0, stream>>>(x, Wpk, Wih0, bih0, bhh0, h0f, N);
    lstm_l1f_kernel<<<ntiles, 512, 0, stream>>>(h0f, Wpk, bih1, bhh1, hbuf, N);

    deg_count_kernel<<<(E + 255) / 256, 256, 0, stream>>>(ei, degi, E);
    row_alloc_kernel<<<(N + 255) / 256, 256, 0, stream>>>(degi, row_ptr, dinv, counter, N);
    csr_fill_kernel<<<(E + 255) / 256, 256, 0, stream>>>(ei, row_ptr, fill, csr_src, E);

    gemm128_kernel<<<(N + 31) / 32, 256, 0, stream>>>(hbuf, W0, buf1h, N);
    agg128_kernel<<<(N + 1) / 2, 256, 0, stream>>>(buf1h, row_ptr, degi, csr_src, dinv, b0, buf2, N, 1);
    gemm128_kernel<<<(N + 31) / 32, 256, 0, stream>>>(buf2, W1, buf1h, N);
    agg128_kernel<<<(N + 1) / 2, 256, 0, stream>>>(buf1h, row_ptr, degi, csr_src, dinv, b1, buf2, N, 1);
    gemm12_kernel<<<((size_t)N * ODIM + 255) / 256, 256, 0, stream>>>(buf2, W2, buf1h, N);
    agg12_kernel<<<((size_t)N * ODIM + 255) / 256, 256, 0, stream>>>(
        buf1h, row_ptr, degi, csr_src, dinv, b2, out, N);
}